// Round 6
// baseline (364.648 us; speedup 1.0000x reference)
//
#include <hip/hip_runtime.h>
#include <math.h>

#define HID 128
#define NF  16
#define NH  4
#define HC  32
#define NLAYERS 4
#define SCAN_B 256   // elements per scan block

// ---------------- init: counts=1 (self-loop) + BN/bias folding ----------------
__global__ void k_init(int* __restrict__ counts, int N,
                       const float* __restrict__ gat_b, const float* __restrict__ gamma,
                       const float* __restrict__ beta, const float* __restrict__ mean,
                       const float* __restrict__ var,
                       float* __restrict__ scale, float* __restrict__ shift) {
    int i = blockIdx.x * blockDim.x + threadIdx.x;
    if (i < N) counts[i] = 1;
    if (i < NLAYERS * HID) {
        float sc = gamma[i] / sqrtf(var[i] + 1e-5f);
        scale[i] = sc;
        shift[i] = beta[i] + (gat_b[i] - mean[i]) * sc;
    }
}

__global__ void k_count_edges(const int* __restrict__ dst, int E, int* __restrict__ counts) {
    int i = blockIdx.x * blockDim.x + threadIdx.x;
    if (i < E) atomicAdd(&counts[dst[i]], 1);
}

// ---------------- two-level multi-block scan ----------------
__global__ __launch_bounds__(SCAN_B) void k_partial(const int* __restrict__ counts,
                                                    int* __restrict__ partials, int N) {
    __shared__ int s[SCAN_B];
    const int t = threadIdx.x;
    const int i = blockIdx.x * SCAN_B + t;
    int v = (i < N) ? counts[i] : 0;
    s[t] = v;
    __syncthreads();
#pragma unroll
    for (int off = SCAN_B / 2; off >= 1; off >>= 1) {
        if (t < off) s[t] += s[t + off];
        __syncthreads();
    }
    if (t == 0) partials[blockIdx.x] = s[0];
}

__global__ __launch_bounds__(128) void k_scanp(const int* __restrict__ partials,
                                               int* __restrict__ bases,
                                               int* __restrict__ row_ptr_N, int B) {
    __shared__ int s[128];
    const int t = threadIdx.x;
    int v = (t < B) ? partials[t] : 0;
    s[t] = v;
    __syncthreads();
    for (int off = 1; off < 128; off <<= 1) {
        int u = (t >= off) ? s[t - off] : 0;
        __syncthreads();
        s[t] += u;
        __syncthreads();
    }
    if (t < B) bases[t] = s[t] - v;          // exclusive
    if (t == 127) *row_ptr_N = s[127];       // total -> row_ptr[N]
}

__global__ __launch_bounds__(SCAN_B) void k_final(const int* __restrict__ counts,
                                                  const int* __restrict__ bases,
                                                  int* __restrict__ row_ptr,
                                                  int* __restrict__ col,
                                                  int* __restrict__ fill, int N) {
    __shared__ int s[SCAN_B];
    const int t = threadIdx.x;
    const int i = blockIdx.x * SCAN_B + t;
    const int v = (i < N) ? counts[i] : 0;
    s[t] = v;
    __syncthreads();
    for (int off = 1; off < SCAN_B; off <<= 1) {
        int u = (t >= off) ? s[t - off] : 0;
        __syncthreads();
        s[t] += u;
        __syncthreads();
    }
    if (i < N) {
        const int row = bases[blockIdx.x] + s[t] - v;   // exclusive prefix
        row_ptr[i] = row;
        col[row] = i;        // self-loop in slot 0
        fill[i] = 1;
    }
}

__global__ void k_scatter(const int* __restrict__ src, const int* __restrict__ dst, int E,
                          const int* __restrict__ row_ptr, int* __restrict__ fill,
                          int* __restrict__ col) {
    int i = blockIdx.x * blockDim.x + threadIdx.x;
    if (i < E) {
        int d = dst[i];
        int pos = atomicAdd(&fill[d], 1);
        col[row_ptr[d] + pos] = src[i];
    }
}

// ---------------- embedding: h = relu(x @ emb_w + emb_b) ----------------
__global__ __launch_bounds__(256) void k_embed(const float* __restrict__ x,
                                               const float* __restrict__ w,
                                               const float* __restrict__ b,
                                               float* __restrict__ h, int N) {
    __shared__ float ws_[NF * HID];
    __shared__ float bs[HID];
    const int t = threadIdx.x;
    for (int i = t; i < NF * HID; i += 256) ws_[i] = w[i];
    if (t < HID) bs[t] = b[t];
    __syncthreads();
    const int n = blockIdx.x * 2 + (t >> 7);
    const int j = t & 127;
    if (n >= N) return;
    float a = bs[j];
    const float4* xp = (const float4*)(x + (size_t)n * NF);
#pragma unroll
    for (int q = 0; q < 4; ++q) {
        const float4 xv = xp[q];
        a = fmaf(xv.x, ws_[(q * 4 + 0) * HID + j], a);
        a = fmaf(xv.y, ws_[(q * 4 + 1) * HID + j], a);
        a = fmaf(xv.z, ws_[(q * 4 + 2) * HID + j], a);
        a = fmaf(xv.w, ws_[(q * 4 + 3) * HID + j], a);
    }
    h[(size_t)n * HID + j] = fmaxf(a, 0.f);
}

// ---------------- per-layer GEMM + attention scores (64x128 tile, dbuf LDS) ----------------
__global__ __launch_bounds__(256) void k_gemm_attn(
    const float* __restrict__ h, const float* __restrict__ W,
    const float* __restrict__ a_src, const float* __restrict__ a_dst,
    float* __restrict__ hproj, float* __restrict__ ssrc, float* __restrict__ sdst, int N) {
    __shared__ float As[2][16][68];     // A^T tile: As[buf][k][m]
    __shared__ float Bs[2][16][132];    // W tile:  Bs[buf][k][j]
    const int tid = threadIdx.x;
    const int m0 = blockIdx.x * 64;
    const int tx = tid & 15;
    const int ty = tid >> 4;
    float acc[4][8];
#pragma unroll
    for (int i = 0; i < 4; ++i)
#pragma unroll
        for (int j = 0; j < 8; ++j) acc[i][j] = 0.f;

    const int arow = tid >> 2;          // 0..63
    const int ak   = (tid & 3) << 2;    // 0,4,8,12
    const int brow = tid >> 4;          // 0..15
    const int bcol = (tid & 15) << 3;   // 0..120
    const int gr = m0 + arow;
    const float* aptr = h + (size_t)gr * HID + ak;
    const float* bptr = W + brow * HID + bcol;

    float4 av = (gr < N) ? *(const float4*)aptr : make_float4(0.f, 0.f, 0.f, 0.f);
    float4 bv0 = *(const float4*)bptr;
    float4 bv1 = *(const float4*)(bptr + 4);
    As[0][ak + 0][arow] = av.x; As[0][ak + 1][arow] = av.y;
    As[0][ak + 2][arow] = av.z; As[0][ak + 3][arow] = av.w;
    *(float4*)&Bs[0][brow][bcol] = bv0;
    *(float4*)&Bs[0][brow][bcol + 4] = bv1;
    __syncthreads();

    for (int k0 = 0; k0 < 8; ++k0) {
        const int cur = k0 & 1, nxt = cur ^ 1;
        if (k0 < 7) {
            av = (gr < N) ? *(const float4*)(aptr + (k0 + 1) * 16)
                          : make_float4(0.f, 0.f, 0.f, 0.f);
            bv0 = *(const float4*)(bptr + (size_t)(k0 + 1) * 16 * HID);
            bv1 = *(const float4*)(bptr + (size_t)(k0 + 1) * 16 * HID + 4);
        }
#pragma unroll
        for (int k = 0; k < 16; ++k) {
            const float4 a  = *(const float4*)&As[cur][k][ty << 2];
            const float4 b0 = *(const float4*)&Bs[cur][k][tx << 3];
            const float4 b1 = *(const float4*)&Bs[cur][k][(tx << 3) + 4];
            const float aa[4] = {a.x, a.y, a.z, a.w};
            const float bb[8] = {b0.x, b0.y, b0.z, b0.w, b1.x, b1.y, b1.z, b1.w};
#pragma unroll
            for (int i = 0; i < 4; ++i)
#pragma unroll
                for (int j = 0; j < 8; ++j) acc[i][j] = fmaf(aa[i], bb[j], acc[i][j]);
        }
        if (k0 < 7) {
            As[nxt][ak + 0][arow] = av.x; As[nxt][ak + 1][arow] = av.y;
            As[nxt][ak + 2][arow] = av.z; As[nxt][ak + 3][arow] = av.w;
            *(float4*)&Bs[nxt][brow][bcol] = bv0;
            *(float4*)&Bs[nxt][brow][bcol + 4] = bv1;
        }
        __syncthreads();
    }

    const int head = tx >> 2;
    float asv[8], adv[8];
#pragma unroll
    for (int j = 0; j < 8; ++j) {
        asv[j] = a_src[head * HC + (tx & 3) * 8 + j];
        adv[j] = a_dst[head * HC + (tx & 3) * 8 + j];
    }
#pragma unroll
    for (int i = 0; i < 4; ++i) {
        const int r = m0 + (ty << 2) + i;
        if (r < N) {
            const float4 o0 = make_float4(acc[i][0], acc[i][1], acc[i][2], acc[i][3]);
            const float4 o1 = make_float4(acc[i][4], acc[i][5], acc[i][6], acc[i][7]);
            *(float4*)(hproj + (size_t)r * HID + (tx << 3)) = o0;
            *(float4*)(hproj + (size_t)r * HID + (tx << 3) + 4) = o1;
            float ps = 0.f, pd = 0.f;
#pragma unroll
            for (int j = 0; j < 8; ++j) {
                ps = fmaf(acc[i][j], asv[j], ps);
                pd = fmaf(acc[i][j], adv[j], pd);
            }
            ps += __shfl_xor(ps, 1); ps += __shfl_xor(ps, 2);
            pd += __shfl_xor(pd, 1); pd += __shfl_xor(pd, 2);
            if ((tx & 3) == 0) { ssrc[r * NH + head] = ps; sdst[r * NH + head] = pd; }
        }
    }
}

// ---------------- fused softmax + aggregation: 128 threads (2 waves) per node ----------------
// Phase A: lane-per-edge (covers deg<=128 in registers), wave butterfly + LDS cross-wave merge.
// Phase B: 4 edges in flight (2 per wave), lane owns a float4 channel group.
#define LEAKY(e) ((e) > 0.f ? (e) : 0.2f * (e))
__global__ __launch_bounds__(128) void k_sagg(
    float* __restrict__ h, const float4* __restrict__ hproj4,
    const float4* __restrict__ ssrc4, const float4* __restrict__ sdst4,
    const int* __restrict__ row_ptr, const int* __restrict__ col,
    const float4* __restrict__ scale4, const float4* __restrict__ shift4, int N) {
    __shared__ int    s_col[128];
    __shared__ float  s_alpha[128 * 4];
    __shared__ float4 s_ms[2];          // per-wave (M or S) 4-head payload
    __shared__ float4 s_red[32];        // cross-wave acc merge
    const int tid = threadIdx.x;        // 0..127
    const int wv  = tid >> 6;           // wave 0/1
    const int lane = tid & 63;
    const int n = blockIdx.x;
    const int beg = row_ptr[n], end = row_ptr[n + 1];
    const int deg = end - beg;
    const float4 sd = sdst4[n];

    // --- phase A1: per-lane edge load + max ---
    const int i0 = beg + tid;
    const bool v0 = i0 < end;
    int sn0 = 0;
    float fe0 = -1e30f, fe1 = -1e30f, fe2 = -1e30f, fe3 = -1e30f;
    float M0 = -1e30f, M1 = -1e30f, M2 = -1e30f, M3 = -1e30f;
    if (v0) {
        sn0 = col[i0];
        const float4 ss = ssrc4[sn0];
        fe0 = LEAKY(ss.x + sd.x); fe1 = LEAKY(ss.y + sd.y);
        fe2 = LEAKY(ss.z + sd.z); fe3 = LEAKY(ss.w + sd.w);
        M0 = fe0; M1 = fe1; M2 = fe2; M3 = fe3;
    }
    for (int i = i0 + 128; i < end; i += 128) {   // deg > 128 (rare)
        const float4 ss = ssrc4[col[i]];
        M0 = fmaxf(M0, LEAKY(ss.x + sd.x));
        M1 = fmaxf(M1, LEAKY(ss.y + sd.y));
        M2 = fmaxf(M2, LEAKY(ss.z + sd.z));
        M3 = fmaxf(M3, LEAKY(ss.w + sd.w));
    }
#pragma unroll
    for (int o = 32; o >= 1; o >>= 1) {
        M0 = fmaxf(M0, __shfl_xor(M0, o));
        M1 = fmaxf(M1, __shfl_xor(M1, o));
        M2 = fmaxf(M2, __shfl_xor(M2, o));
        M3 = fmaxf(M3, __shfl_xor(M3, o));
    }
    if (lane == 0) s_ms[wv] = make_float4(M0, M1, M2, M3);
    __syncthreads();
    {
        const float4 mo = s_ms[wv ^ 1];
        M0 = fmaxf(M0, mo.x); M1 = fmaxf(M1, mo.y);
        M2 = fmaxf(M2, mo.z); M3 = fmaxf(M3, mo.w);
    }
    __syncthreads();   // s_ms reuse below

    // --- phase A2: exp + sum ---
    float t0 = 0.f, t1 = 0.f, t2 = 0.f, t3 = 0.f;
    float S0 = 0.f, S1 = 0.f, S2 = 0.f, S3 = 0.f;
    if (v0) {
        t0 = __expf(fe0 - M0); t1 = __expf(fe1 - M1);
        t2 = __expf(fe2 - M2); t3 = __expf(fe3 - M3);
        S0 = t0; S1 = t1; S2 = t2; S3 = t3;
    }
    for (int i = i0 + 128; i < end; i += 128) {   // deg > 128 (rare)
        const float4 ss = ssrc4[col[i]];
        S0 += __expf(LEAKY(ss.x + sd.x) - M0);
        S1 += __expf(LEAKY(ss.y + sd.y) - M1);
        S2 += __expf(LEAKY(ss.z + sd.z) - M2);
        S3 += __expf(LEAKY(ss.w + sd.w) - M3);
    }
#pragma unroll
    for (int o = 32; o >= 1; o >>= 1) {
        S0 += __shfl_xor(S0, o);
        S1 += __shfl_xor(S1, o);
        S2 += __shfl_xor(S2, o);
        S3 += __shfl_xor(S3, o);
    }
    if (lane == 0) s_ms[wv] = make_float4(S0, S1, S2, S3);
    __syncthreads();
    {
        const float4 so = s_ms[wv ^ 1];
        S0 += so.x; S1 += so.y; S2 += so.z; S3 += so.w;
    }
    const float inv0 = 1.f / (S0 + 1e-16f);
    const float inv1 = 1.f / (S1 + 1e-16f);
    const float inv2 = 1.f / (S2 + 1e-16f);
    const float inv3 = 1.f / (S3 + 1e-16f);

    // --- stage chunk 0 (alpha from registers) ---
    if (v0) {
        s_col[tid] = sn0;
        float4 a;
        a.x = t0 * inv0; a.y = t1 * inv1; a.z = t2 * inv2; a.w = t3 * inv3;
        *(float4*)&s_alpha[tid << 2] = a;
    }
    __syncthreads();

    // --- phase B: weighted gather, 4 edges in flight (slot = wv*2 + eh) ---
    const int c    = lane & 31;          // float4 channel group
    const int hh   = c >> 3;             // head
    const int slot = (wv << 1) | (lane >> 5);
    float4 acc = make_float4(0.f, 0.f, 0.f, 0.f);
    {
        const int cnt = min(128, deg);
#pragma unroll 4
        for (int j4 = 0; j4 < cnt; j4 += 4) {
            const int j = j4 + slot;
            float a = 0.f; int sn = s_col[0];
            if (j < cnt) { sn = s_col[j]; a = s_alpha[(j << 2) | hh]; }
            const float4 hv = hproj4[(size_t)sn * 32 + c];
            acc.x = fmaf(a, hv.x, acc.x);
            acc.y = fmaf(a, hv.y, acc.y);
            acc.z = fmaf(a, hv.z, acc.z);
            acc.w = fmaf(a, hv.w, acc.w);
        }
    }
    // deg > 128: per-chunk re-stage (node-uniform trip count -> barriers safe)
    for (int c0 = beg + 128; c0 < end; c0 += 128) {
        __syncthreads();   // previous-chunk gathers done before overwrite
        const int i = c0 + tid;
        if (i < end) {
            const int sn = col[i];
            const float4 ss = ssrc4[sn];
            float4 a;
            a.x = __expf(LEAKY(ss.x + sd.x) - M0) * inv0;
            a.y = __expf(LEAKY(ss.y + sd.y) - M1) * inv1;
            a.z = __expf(LEAKY(ss.z + sd.z) - M2) * inv2;
            a.w = __expf(LEAKY(ss.w + sd.w) - M3) * inv3;
            s_col[tid] = sn;
            *(float4*)&s_alpha[tid << 2] = a;
        }
        __syncthreads();
        const int cnt = min(128, end - c0);
#pragma unroll 4
        for (int j4 = 0; j4 < cnt; j4 += 4) {
            const int j = j4 + slot;
            float a = 0.f; int sn = s_col[0];
            if (j < cnt) { sn = s_col[j]; a = s_alpha[(j << 2) | hh]; }
            const float4 hv = hproj4[(size_t)sn * 32 + c];
            acc.x = fmaf(a, hv.x, acc.x);
            acc.y = fmaf(a, hv.y, acc.y);
            acc.z = fmaf(a, hv.z, acc.z);
            acc.w = fmaf(a, hv.w, acc.w);
        }
    }
    // merge: intra-wave (edge slots), then cross-wave via LDS
    acc.x += __shfl_xor(acc.x, 32);
    acc.y += __shfl_xor(acc.y, 32);
    acc.z += __shfl_xor(acc.z, 32);
    acc.w += __shfl_xor(acc.w, 32);
    if (wv == 1 && lane < 32) s_red[c] = acc;
    __syncthreads();
    if (wv == 0 && lane < 32) {
        const float4 r = s_red[c];
        acc.x += r.x; acc.y += r.y; acc.z += r.z; acc.w += r.w;
        const float4 sc = scale4[c];
        const float4 sh = shift4[c];
        float4* hp = (float4*)h + (size_t)n * 32 + c;
        float4 hv = *hp;
        hv.x += fmaxf(fmaf(acc.x, sc.x, sh.x), 0.f);
        hv.y += fmaxf(fmaf(acc.y, sc.y, sh.y), 0.f);
        hv.z += fmaxf(fmaf(acc.z, sc.z, sh.z), 0.f);
        hv.w += fmaxf(fmaf(acc.w, sc.w, sh.w), 0.f);
        *hp = hv;
    }
}

// ---------------- fused mean pool + MLP head (one block per graph) ----------------
__global__ __launch_bounds__(256) void k_poolhead(
    const float4* __restrict__ h4, const int* __restrict__ batch,
    const float* __restrict__ w1, const float* __restrict__ b1,
    const float* __restrict__ w2, const float* __restrict__ b2,
    const float* __restrict__ w3, const float* __restrict__ b3,
    float* __restrict__ out, int N) {
    __shared__ float4 red[8][32];
    __shared__ float gp[HID];
    __shared__ float l1[64];
    __shared__ float l2[32];
    const int g = blockIdx.x;
    const int t = threadIdx.x;
    const int c4 = t & 31, r = t >> 5;
    int lo = 0, hi = N;
    while (lo < hi) { int mid = (lo + hi) >> 1; if (batch[mid] < g) lo = mid + 1; else hi = mid; }
    int lo2 = lo, hi2 = N;
    while (lo2 < hi2) { int mid = (lo2 + hi2) >> 1; if (batch[mid] < g + 1) lo2 = mid + 1; else hi2 = mid; }
    float4 acc = make_float4(0.f, 0.f, 0.f, 0.f);
    for (int i = lo + r; i < lo2; i += 8) {
        const float4 v = h4[(size_t)i * 32 + c4];
        acc.x += v.x; acc.y += v.y; acc.z += v.z; acc.w += v.w;
    }
    red[r][c4] = acc;
    __syncthreads();
    if (r == 0) {
#pragma unroll
        for (int k = 1; k < 8; ++k) {
            const float4 v = red[k][c4];
            acc.x += v.x; acc.y += v.y; acc.z += v.z; acc.w += v.w;
        }
        const float invc = 1.f / fmaxf((float)(lo2 - lo), 1.f);
        float4 o = make_float4(acc.x * invc, acc.y * invc, acc.z * invc, acc.w * invc);
        *(float4*)&gp[c4 << 2] = o;
    }
    __syncthreads();
    if (t < 64) {
        float a = b1[t];
        for (int k = 0; k < HID; ++k) a = fmaf(gp[k], w1[k * 64 + t], a);
        l1[t] = fmaxf(a, 0.f);
    }
    __syncthreads();
    if (t < 32) {
        float a2 = b2[t];
        for (int k = 0; k < 64; ++k) a2 = fmaf(l1[k], w2[k * 32 + t], a2);
        l2[t] = fmaxf(a2, 0.f);
    }
    __syncthreads();
    if (t == 0) {
        float a3 = b3[0];
        for (int k = 0; k < 32; ++k) a3 = fmaf(l2[k], w3[k], a3);
        out[g] = a3;
    }
}

extern "C" void kernel_launch(void* const* d_in, const int* in_sizes, int n_in,
                              void* d_out, int out_size, void* d_ws, size_t ws_size,
                              hipStream_t stream) {
    const float* x        = (const float*)d_in[0];
    const int*   eidx     = (const int*)d_in[1];
    const int*   batch    = (const int*)d_in[2];
    const float* emb_w    = (const float*)d_in[3];
    const float* emb_b    = (const float*)d_in[4];
    const float* gat_w    = (const float*)d_in[5];
    const float* att_src  = (const float*)d_in[6];
    const float* att_dst  = (const float*)d_in[7];
    const float* gat_b    = (const float*)d_in[8];
    const float* bn_gamma = (const float*)d_in[9];
    const float* bn_beta  = (const float*)d_in[10];
    const float* bn_mean  = (const float*)d_in[11];
    const float* bn_var   = (const float*)d_in[12];
    const float* fc1_w    = (const float*)d_in[13];
    const float* fc1_b    = (const float*)d_in[14];
    const float* fc2_w    = (const float*)d_in[15];
    const float* fc2_b    = (const float*)d_in[16];
    const float* bg_w     = (const float*)d_in[17];
    const float* bg_b     = (const float*)d_in[18];
    float* out = (float*)d_out;

    const int N = in_sizes[0] / NF;
    const int E = in_sizes[1] / 2;
    const int G = out_size;

    const int* esrc = eidx;
    const int* edst = eidx + E;

    char* ws = (char*)d_ws;
    size_t off = 0;
    auto alloc = [&](size_t bytes) -> void* {
        void* p = ws + off;
        off += (bytes + 255) & ~(size_t)255;
        return p;
    };
    float*  h        = (float*)alloc((size_t)N * HID * sizeof(float));
    float*  hproj    = (float*)alloc((size_t)N * HID * sizeof(float));
    float*  ssrc     = (float*)alloc((size_t)N * NH * sizeof(float));
    float*  sdst     = (float*)alloc((size_t)N * NH * sizeof(float));
    float*  bnscale  = (float*)alloc((size_t)NLAYERS * HID * sizeof(float));
    float*  bnshift  = (float*)alloc((size_t)NLAYERS * HID * sizeof(float));
    int*    row_ptr  = (int*)alloc((size_t)(N + 1) * sizeof(int));
    int*    counts   = (int*)alloc((size_t)N * sizeof(int));   // reused as fill
    int*    col      = (int*)alloc((size_t)(E + N) * sizeof(int));
    int*    partials = (int*)alloc(1024 * sizeof(int));
    int*    bases    = (int*)alloc(1024 * sizeof(int));
    (void)ws_size; (void)n_in;

    const int TB = 256;
    const int NB = (N + SCAN_B - 1) / SCAN_B;   // 79 for N=20000 (<=128 required)

    k_init<<<(N + TB - 1) / TB, TB, 0, stream>>>(counts, N, gat_b, bn_gamma, bn_beta,
                                                 bn_mean, bn_var, bnscale, bnshift);
    k_count_edges<<<(E + TB - 1) / TB, TB, 0, stream>>>(edst, E, counts);
    k_partial<<<NB, SCAN_B, 0, stream>>>(counts, partials, N);
    k_scanp<<<1, 128, 0, stream>>>(partials, bases, row_ptr + N, NB);
    k_final<<<NB, SCAN_B, 0, stream>>>(counts, bases, row_ptr, col, counts, N);
    k_scatter<<<(E + TB - 1) / TB, TB, 0, stream>>>(esrc, edst, E, row_ptr, counts, col);

    k_embed<<<(N + 1) / 2, 256, 0, stream>>>(x, emb_w, emb_b, h, N);

    for (int l = 0; l < NLAYERS; ++l) {
        k_gemm_attn<<<(N + 63) / 64, 256, 0, stream>>>(
            h, gat_w + (size_t)l * HID * HID,
            att_src + (size_t)l * NH * HC, att_dst + (size_t)l * NH * HC,
            hproj, ssrc, sdst, N);
        k_sagg<<<N, 128, 0, stream>>>(
            h, (const float4*)hproj, (const float4*)ssrc, (const float4*)sdst,
            row_ptr, col,
            (const float4*)(bnscale + l * HID), (const float4*)(bnshift + l * HID), N);
    }

    k_poolhead<<<G, 256, 0, stream>>>((const float4*)h, batch,
                                      fc1_w, fc1_b, fc2_w, fc2_b, bg_w, bg_b, out, N);
}

// Round 7
// 344.835 us; speedup vs baseline: 1.0575x; 1.0575x over previous
//
#include <hip/hip_runtime.h>
#include <math.h>

#define HID 128
#define NF  16
#define NH  4
#define HC  32
#define NLAYERS 4
#define SCAN_B 256   // elements per scan block

// ---------------- init: counts=1 (self-loop) + BN/bias folding ----------------
__global__ void k_init(int* __restrict__ counts, int N,
                       const float* __restrict__ gat_b, const float* __restrict__ gamma,
                       const float* __restrict__ beta, const float* __restrict__ mean,
                       const float* __restrict__ var,
                       float* __restrict__ scale, float* __restrict__ shift) {
    int i = blockIdx.x * blockDim.x + threadIdx.x;
    if (i < N) counts[i] = 1;
    if (i < NLAYERS * HID) {
        float sc = gamma[i] / sqrtf(var[i] + 1e-5f);
        scale[i] = sc;
        shift[i] = beta[i] + (gat_b[i] - mean[i]) * sc;
    }
}

__global__ void k_count_edges(const int* __restrict__ dst, int E, int* __restrict__ counts) {
    int i = blockIdx.x * blockDim.x + threadIdx.x;
    if (i < E) atomicAdd(&counts[dst[i]], 1);
}

// ---------------- two-level multi-block scan ----------------
__global__ __launch_bounds__(SCAN_B) void k_partial(const int* __restrict__ counts,
                                                    int* __restrict__ partials, int N) {
    __shared__ int s[SCAN_B];
    const int t = threadIdx.x;
    const int i = blockIdx.x * SCAN_B + t;
    int v = (i < N) ? counts[i] : 0;
    s[t] = v;
    __syncthreads();
#pragma unroll
    for (int off = SCAN_B / 2; off >= 1; off >>= 1) {
        if (t < off) s[t] += s[t + off];
        __syncthreads();
    }
    if (t == 0) partials[blockIdx.x] = s[0];
}

__global__ __launch_bounds__(128) void k_scanp(const int* __restrict__ partials,
                                               int* __restrict__ bases,
                                               int* __restrict__ row_ptr_N, int B) {
    __shared__ int s[128];
    const int t = threadIdx.x;
    int v = (t < B) ? partials[t] : 0;
    s[t] = v;
    __syncthreads();
    for (int off = 1; off < 128; off <<= 1) {
        int u = (t >= off) ? s[t - off] : 0;
        __syncthreads();
        s[t] += u;
        __syncthreads();
    }
    if (t < B) bases[t] = s[t] - v;          // exclusive
    if (t == 127) *row_ptr_N = s[127];       // total -> row_ptr[N]
}

__global__ __launch_bounds__(SCAN_B) void k_final(const int* __restrict__ counts,
                                                  const int* __restrict__ bases,
                                                  int* __restrict__ row_ptr,
                                                  int* __restrict__ col,
                                                  int* __restrict__ fill, int N) {
    __shared__ int s[SCAN_B];
    const int t = threadIdx.x;
    const int i = blockIdx.x * SCAN_B + t;
    const int v = (i < N) ? counts[i] : 0;
    s[t] = v;
    __syncthreads();
    for (int off = 1; off < SCAN_B; off <<= 1) {
        int u = (t >= off) ? s[t - off] : 0;
        __syncthreads();
        s[t] += u;
        __syncthreads();
    }
    if (i < N) {
        const int row = bases[blockIdx.x] + s[t] - v;   // exclusive prefix
        row_ptr[i] = row;
        col[row] = i;        // self-loop in slot 0
        fill[i] = 1;
    }
}

__global__ void k_scatter(const int* __restrict__ src, const int* __restrict__ dst, int E,
                          const int* __restrict__ row_ptr, int* __restrict__ fill,
                          int* __restrict__ col) {
    int i = blockIdx.x * blockDim.x + threadIdx.x;
    if (i < E) {
        int d = dst[i];
        int pos = atomicAdd(&fill[d], 1);
        col[row_ptr[d] + pos] = src[i];
    }
}

// ---------------- embedding: h = relu(x @ emb_w + emb_b) ----------------
__global__ __launch_bounds__(256) void k_embed(const float* __restrict__ x,
                                               const float* __restrict__ w,
                                               const float* __restrict__ b,
                                               float* __restrict__ h, int N) {
    __shared__ float ws_[NF * HID];
    __shared__ float bs[HID];
    const int t = threadIdx.x;
    for (int i = t; i < NF * HID; i += 256) ws_[i] = w[i];
    if (t < HID) bs[t] = b[t];
    __syncthreads();
    const int n = blockIdx.x * 2 + (t >> 7);
    const int j = t & 127;
    if (n >= N) return;
    float a = bs[j];
    const float4* xp = (const float4*)(x + (size_t)n * NF);
#pragma unroll
    for (int q = 0; q < 4; ++q) {
        const float4 xv = xp[q];
        a = fmaf(xv.x, ws_[(q * 4 + 0) * HID + j], a);
        a = fmaf(xv.y, ws_[(q * 4 + 1) * HID + j], a);
        a = fmaf(xv.z, ws_[(q * 4 + 2) * HID + j], a);
        a = fmaf(xv.w, ws_[(q * 4 + 3) * HID + j], a);
    }
    h[(size_t)n * HID + j] = fmaxf(a, 0.f);
}

// ---------------- per-layer GEMM + attention scores (64x128 tile, single buffer) ----------------
__global__ __launch_bounds__(256) void k_gemm_attn(
    const float* __restrict__ h, const float* __restrict__ W,
    const float* __restrict__ a_src, const float* __restrict__ a_dst,
    float* __restrict__ hproj, float* __restrict__ ssrc, float* __restrict__ sdst, int N) {
    __shared__ float As[16][68];    // A^T tile: As[k][m]
    __shared__ float Bs[16][132];   // W tile: Bs[k][j]
    const int tid = threadIdx.x;
    const int m0 = blockIdx.x * 64;
    const int tx = tid & 15;
    const int ty = tid >> 4;
    float acc[4][8];
#pragma unroll
    for (int i = 0; i < 4; ++i)
#pragma unroll
        for (int j = 0; j < 8; ++j) acc[i][j] = 0.f;

    const int arow = tid >> 2;          // 0..63
    const int ak   = (tid & 3) << 2;    // 0,4,8,12
    const int brow = tid >> 4;          // 0..15
    const int bcol = (tid & 15) << 3;   // 0..120
    const int gr = m0 + arow;

    for (int k0 = 0; k0 < HID; k0 += 16) {
        float4 av = make_float4(0.f, 0.f, 0.f, 0.f);
        if (gr < N) av = *(const float4*)(h + (size_t)gr * HID + k0 + ak);
        const float4 bv0 = *(const float4*)(W + (k0 + brow) * HID + bcol);
        const float4 bv1 = *(const float4*)(W + (k0 + brow) * HID + bcol + 4);
        __syncthreads();
        As[ak + 0][arow] = av.x; As[ak + 1][arow] = av.y;
        As[ak + 2][arow] = av.z; As[ak + 3][arow] = av.w;
        *(float4*)&Bs[brow][bcol] = bv0;
        *(float4*)&Bs[brow][bcol + 4] = bv1;
        __syncthreads();
#pragma unroll
        for (int k = 0; k < 16; ++k) {
            const float4 a  = *(const float4*)&As[k][ty << 2];
            const float4 b0 = *(const float4*)&Bs[k][tx << 3];
            const float4 b1 = *(const float4*)&Bs[k][(tx << 3) + 4];
            const float aa[4] = {a.x, a.y, a.z, a.w};
            const float bb[8] = {b0.x, b0.y, b0.z, b0.w, b1.x, b1.y, b1.z, b1.w};
#pragma unroll
            for (int i = 0; i < 4; ++i)
#pragma unroll
                for (int j = 0; j < 8; ++j) acc[i][j] = fmaf(aa[i], bb[j], acc[i][j]);
        }
    }

    const int head = tx >> 2;
    float asv[8], adv[8];
#pragma unroll
    for (int j = 0; j < 8; ++j) {
        asv[j] = a_src[head * HC + (tx & 3) * 8 + j];
        adv[j] = a_dst[head * HC + (tx & 3) * 8 + j];
    }
#pragma unroll
    for (int i = 0; i < 4; ++i) {
        const int r = m0 + (ty << 2) + i;
        if (r < N) {
            const float4 o0 = make_float4(acc[i][0], acc[i][1], acc[i][2], acc[i][3]);
            const float4 o1 = make_float4(acc[i][4], acc[i][5], acc[i][6], acc[i][7]);
            *(float4*)(hproj + (size_t)r * HID + (tx << 3)) = o0;
            *(float4*)(hproj + (size_t)r * HID + (tx << 3) + 4) = o1;
            float ps = 0.f, pd = 0.f;
#pragma unroll
            for (int j = 0; j < 8; ++j) {
                ps = fmaf(acc[i][j], asv[j], ps);
                pd = fmaf(acc[i][j], adv[j], pd);
            }
            ps += __shfl_xor(ps, 1); ps += __shfl_xor(ps, 2);
            pd += __shfl_xor(pd, 1); pd += __shfl_xor(pd, 2);
            if ((tx & 3) == 0) { ssrc[r * NH + head] = ps; sdst[r * NH + head] = pd; }
        }
    }
}

// ---------------- fused softmax + aggregation: one 64-lane wave per node ----------------
// Phase A: exact segment max (butterfly fmax) then exp-sum (butterfly add).
// Phase B: per 64-edge chunk, stash col/alpha in wave-private LDS, then all 64
//          lanes stream the full hproj row (float2/lane) per edge.
#define LEAKY(e) ((e) > 0.f ? (e) : 0.2f * (e))
__global__ __launch_bounds__(256) void k_sagg(
    float* __restrict__ h, const float2* __restrict__ hproj2,
    const float4* __restrict__ ssrc4, const float4* __restrict__ sdst4,
    const int* __restrict__ row_ptr, const int* __restrict__ col,
    const float2* __restrict__ scale2, const float2* __restrict__ shift2, int N) {
    __shared__ int   s_col[4][64];
    __shared__ float s_alpha[4][64 * 4];
    const int t = threadIdx.x;
    const int w = t >> 6;
    const int lane = t & 63;
    const int n = blockIdx.x * 4 + w;
    if (n >= N) return;
    const int beg = row_ptr[n], end = row_ptr[n + 1];
    const float4 sd = sdst4[n];

    // --- phase A1: max ---
    const int i0 = beg + lane;
    const bool v0 = i0 < end;
    int sn0 = 0;
    float fe0 = -1e30f, fe1 = -1e30f, fe2 = -1e30f, fe3 = -1e30f;
    float M0 = -1e30f, M1 = -1e30f, M2 = -1e30f, M3 = -1e30f;
    if (v0) {
        sn0 = col[i0];
        const float4 ss = ssrc4[sn0];
        fe0 = LEAKY(ss.x + sd.x); fe1 = LEAKY(ss.y + sd.y);
        fe2 = LEAKY(ss.z + sd.z); fe3 = LEAKY(ss.w + sd.w);
        M0 = fe0; M1 = fe1; M2 = fe2; M3 = fe3;
    }
    for (int i = i0 + 64; i < end; i += 64) {
        const float4 ss = ssrc4[col[i]];
        M0 = fmaxf(M0, LEAKY(ss.x + sd.x));
        M1 = fmaxf(M1, LEAKY(ss.y + sd.y));
        M2 = fmaxf(M2, LEAKY(ss.z + sd.z));
        M3 = fmaxf(M3, LEAKY(ss.w + sd.w));
    }
#pragma unroll
    for (int o = 32; o >= 1; o >>= 1) {
        M0 = fmaxf(M0, __shfl_xor(M0, o));
        M1 = fmaxf(M1, __shfl_xor(M1, o));
        M2 = fmaxf(M2, __shfl_xor(M2, o));
        M3 = fmaxf(M3, __shfl_xor(M3, o));
    }
    // --- phase A2: exp-sum (cache own-edge exp for chunk 0 alpha) ---
    float S0 = 0.f, S1 = 0.f, S2 = 0.f, S3 = 0.f;
    float t0 = 0.f, t1 = 0.f, t2 = 0.f, t3 = 0.f;
    if (v0) {
        t0 = __expf(fe0 - M0); t1 = __expf(fe1 - M1);
        t2 = __expf(fe2 - M2); t3 = __expf(fe3 - M3);
        S0 = t0; S1 = t1; S2 = t2; S3 = t3;
    }
    for (int i = i0 + 64; i < end; i += 64) {
        const float4 ss = ssrc4[col[i]];
        S0 += __expf(LEAKY(ss.x + sd.x) - M0);
        S1 += __expf(LEAKY(ss.y + sd.y) - M1);
        S2 += __expf(LEAKY(ss.z + sd.z) - M2);
        S3 += __expf(LEAKY(ss.w + sd.w) - M3);
    }
#pragma unroll
    for (int o = 32; o >= 1; o >>= 1) {
        S0 += __shfl_xor(S0, o);
        S1 += __shfl_xor(S1, o);
        S2 += __shfl_xor(S2, o);
        S3 += __shfl_xor(S3, o);
    }
    const float inv0 = 1.f / (S0 + 1e-16f);
    const float inv1 = 1.f / (S1 + 1e-16f);
    const float inv2 = 1.f / (S2 + 1e-16f);
    const float inv3 = 1.f / (S3 + 1e-16f);

    // --- phase B: weighted gather ---
    const int hh = lane >> 4;   // this lane's head (channels 2*lane, 2*lane+1)
    float2 acc = make_float2(0.f, 0.f);
    // chunk 0 (alpha from cached registers)
    {
        if (v0) {
            s_col[w][lane] = sn0;
            float4 a;
            a.x = t0 * inv0; a.y = t1 * inv1; a.z = t2 * inv2; a.w = t3 * inv3;
            *(float4*)&s_alpha[w][lane << 2] = a;
        }
        asm volatile("s_waitcnt lgkmcnt(0)" ::: "memory");
        const int cnt = min(64, end - beg);
#pragma unroll 4
        for (int j = 0; j < cnt; ++j) {
            const int sn = s_col[w][j];
            const float a = s_alpha[w][(j << 2) | hh];
            const float2 hv = hproj2[(size_t)sn * 64 + lane];
            acc.x = fmaf(a, hv.x, acc.x);
            acc.y = fmaf(a, hv.y, acc.y);
        }
    }
    // remaining chunks (rare: deg > 64)
    for (int c0 = beg + 64; c0 < end; c0 += 64) {
        const int i = c0 + lane;
        if (i < end) {
            const int sn = col[i];
            const float4 ss = ssrc4[sn];
            float4 a;
            a.x = __expf(LEAKY(ss.x + sd.x) - M0) * inv0;
            a.y = __expf(LEAKY(ss.y + sd.y) - M1) * inv1;
            a.z = __expf(LEAKY(ss.z + sd.z) - M2) * inv2;
            a.w = __expf(LEAKY(ss.w + sd.w) - M3) * inv3;
            s_col[w][lane] = sn;
            *(float4*)&s_alpha[w][lane << 2] = a;
        }
        asm volatile("s_waitcnt lgkmcnt(0)" ::: "memory");
        const int cnt = min(64, end - c0);
#pragma unroll 4
        for (int j = 0; j < cnt; ++j) {
            const int sn = s_col[w][j];
            const float a = s_alpha[w][(j << 2) | hh];
            const float2 hv = hproj2[(size_t)sn * 64 + lane];
            acc.x = fmaf(a, hv.x, acc.x);
            acc.y = fmaf(a, hv.y, acc.y);
        }
    }

    // --- epilogue: BN + ReLU + residual ---
    const float2 sc = scale2[lane];
    const float2 sh = shift2[lane];
    float2* hp = (float2*)h + (size_t)n * 64 + lane;
    float2 hv = *hp;
    hv.x += fmaxf(fmaf(acc.x, sc.x, sh.x), 0.f);
    hv.y += fmaxf(fmaf(acc.y, sc.y, sh.y), 0.f);
    *hp = hv;
}

// ---------------- fused mean pool + MLP head (one block per graph) ----------------
__global__ __launch_bounds__(256) void k_poolhead(
    const float4* __restrict__ h4, const int* __restrict__ batch,
    const float* __restrict__ w1, const float* __restrict__ b1,
    const float* __restrict__ w2, const float* __restrict__ b2,
    const float* __restrict__ w3, const float* __restrict__ b3,
    float* __restrict__ out, int N) {
    __shared__ float4 red[8][32];
    __shared__ float gp[HID];
    __shared__ float l1[64];
    __shared__ float l2[32];
    const int g = blockIdx.x;
    const int t = threadIdx.x;
    const int c4 = t & 31, r = t >> 5;
    int lo = 0, hi = N;
    while (lo < hi) { int mid = (lo + hi) >> 1; if (batch[mid] < g) lo = mid + 1; else hi = mid; }
    int lo2 = lo, hi2 = N;
    while (lo2 < hi2) { int mid = (lo2 + hi2) >> 1; if (batch[mid] < g + 1) lo2 = mid + 1; else hi2 = mid; }
    float4 acc = make_float4(0.f, 0.f, 0.f, 0.f);
    for (int i = lo + r; i < lo2; i += 8) {
        const float4 v = h4[(size_t)i * 32 + c4];
        acc.x += v.x; acc.y += v.y; acc.z += v.z; acc.w += v.w;
    }
    red[r][c4] = acc;
    __syncthreads();
    if (r == 0) {
#pragma unroll
        for (int k = 1; k < 8; ++k) {
            const float4 v = red[k][c4];
            acc.x += v.x; acc.y += v.y; acc.z += v.z; acc.w += v.w;
        }
        const float invc = 1.f / fmaxf((float)(lo2 - lo), 1.f);
        float4 o = make_float4(acc.x * invc, acc.y * invc, acc.z * invc, acc.w * invc);
        *(float4*)&gp[c4 << 2] = o;
    }
    __syncthreads();
    if (t < 64) {
        float a = b1[t];
        for (int k = 0; k < HID; ++k) a = fmaf(gp[k], w1[k * 64 + t], a);
        l1[t] = fmaxf(a, 0.f);
    }
    __syncthreads();
    if (t < 32) {
        float a2 = b2[t];
        for (int k = 0; k < 64; ++k) a2 = fmaf(l1[k], w2[k * 32 + t], a2);
        l2[t] = fmaxf(a2, 0.f);
    }
    __syncthreads();
    if (t == 0) {
        float a3 = b3[0];
        for (int k = 0; k < 32; ++k) a3 = fmaf(l2[k], w3[k], a3);
        out[g] = a3;
    }
}

extern "C" void kernel_launch(void* const* d_in, const int* in_sizes, int n_in,
                              void* d_out, int out_size, void* d_ws, size_t ws_size,
                              hipStream_t stream) {
    const float* x        = (const float*)d_in[0];
    const int*   eidx     = (const int*)d_in[1];
    const int*   batch    = (const int*)d_in[2];
    const float* emb_w    = (const float*)d_in[3];
    const float* emb_b    = (const float*)d_in[4];
    const float* gat_w    = (const float*)d_in[5];
    const float* att_src  = (const float*)d_in[6];
    const float* att_dst  = (const float*)d_in[7];
    const float* gat_b    = (const float*)d_in[8];
    const float* bn_gamma = (const float*)d_in[9];
    const float* bn_beta  = (const float*)d_in[10];
    const float* bn_mean  = (const float*)d_in[11];
    const float* bn_var   = (const float*)d_in[12];
    const float* fc1_w    = (const float*)d_in[13];
    const float* fc1_b    = (const float*)d_in[14];
    const float* fc2_w    = (const float*)d_in[15];
    const float* fc2_b    = (const float*)d_in[16];
    const float* bg_w     = (const float*)d_in[17];
    const float* bg_b     = (const float*)d_in[18];
    float* out = (float*)d_out;

    const int N = in_sizes[0] / NF;
    const int E = in_sizes[1] / 2;
    const int G = out_size;

    const int* esrc = eidx;
    const int* edst = eidx + E;

    char* ws = (char*)d_ws;
    size_t off = 0;
    auto alloc = [&](size_t bytes) -> void* {
        void* p = ws + off;
        off += (bytes + 255) & ~(size_t)255;
        return p;
    };
    float*  h        = (float*)alloc((size_t)N * HID * sizeof(float));
    float*  hproj    = (float*)alloc((size_t)N * HID * sizeof(float));
    float*  ssrc     = (float*)alloc((size_t)N * NH * sizeof(float));
    float*  sdst     = (float*)alloc((size_t)N * NH * sizeof(float));
    float*  bnscale  = (float*)alloc((size_t)NLAYERS * HID * sizeof(float));
    float*  bnshift  = (float*)alloc((size_t)NLAYERS * HID * sizeof(float));
    int*    row_ptr  = (int*)alloc((size_t)(N + 1) * sizeof(int));
    int*    counts   = (int*)alloc((size_t)N * sizeof(int));   // reused as fill
    int*    col      = (int*)alloc((size_t)(E + N) * sizeof(int));
    int*    partials = (int*)alloc(1024 * sizeof(int));
    int*    bases    = (int*)alloc(1024 * sizeof(int));
    (void)ws_size; (void)n_in;

    const int TB = 256;
    const int NB = (N + SCAN_B - 1) / SCAN_B;   // 79 for N=20000 (<=128 required)

    k_init<<<(N + TB - 1) / TB, TB, 0, stream>>>(counts, N, gat_b, bn_gamma, bn_beta,
                                                 bn_mean, bn_var, bnscale, bnshift);
    k_count_edges<<<(E + TB - 1) / TB, TB, 0, stream>>>(edst, E, counts);
    k_partial<<<NB, SCAN_B, 0, stream>>>(counts, partials, N);
    k_scanp<<<1, 128, 0, stream>>>(partials, bases, row_ptr + N, NB);
    k_final<<<NB, SCAN_B, 0, stream>>>(counts, bases, row_ptr, col, counts, N);
    k_scatter<<<(E + TB - 1) / TB, TB, 0, stream>>>(esrc, edst, E, row_ptr, counts, col);

    k_embed<<<(N + 1) / 2, 256, 0, stream>>>(x, emb_w, emb_b, h, N);

    for (int l = 0; l < NLAYERS; ++l) {
        k_gemm_attn<<<(N + 63) / 64, 256, 0, stream>>>(
            h, gat_w + (size_t)l * HID * HID,
            att_src + (size_t)l * NH * HC, att_dst + (size_t)l * NH * HC,
            hproj, ssrc, sdst, N);
        k_sagg<<<(N + 3) / 4, 256, 0, stream>>>(
            h, (const float2*)hproj, (const float4*)ssrc, (const float4*)sdst,
            row_ptr, col,
            (const float2*)(bnscale + l * HID), (const float2*)(bnshift + l * HID), N);
    }

    k_poolhead<<<G, 256, 0, stream>>>((const float4*)h, batch,
                                      fc1_w, fc1_b, fc2_w, fc2_b, bg_w, bg_b, out, N);
}